// Round 7
// baseline (9787.971 us; speedup 1.0000x reference)
//
#include <hip/hip_runtime.h>
#include <hip/hip_bf16.h>

using bf16 = __hip_bfloat16;
typedef __attribute__((ext_vector_type(8))) short short8;   // 8 bf16 = 16B
typedef __attribute__((ext_vector_type(4))) float f32x4;

constexpr int kT = 256, kB = 32, kIN = 1024, kH = 1024, kG = 4096;
constexpr int kBH = kB * kH;  // 32768
constexpr int kNB = kH / 16;  // 64 blocks per scan

__device__ inline f32x4 mfma16(short8 a, short8 b, f32x4 c) {
    return __builtin_amdgcn_mfma_f32_16x16x32_bf16(a, b, c, 0, 0, 0);
}
__device__ inline short8 ld8(const bf16* p) {
    return *reinterpret_cast<const short8*>(p);
}
__device__ inline float sigmoidf(float x) { return 1.f / (1.f + expf(-x)); }

// ---------- prep: fp32 -> bf16 ----------
__global__ void cvt_f32_bf16(const float* __restrict__ in,
                             bf16* __restrict__ outp, int n) {
    for (int i = blockIdx.x * blockDim.x + threadIdx.x; i < n;
         i += gridDim.x * blockDim.x)
        outp[i] = __float2bfloat16(in[i]);
}

// ---------- big GEMM: C[M,N] f32 = A[M,K]bf16 @ Bm[N,K]^T bf16 + b1+b2 ----------
__global__ __launch_bounds__(64)
void gemm_bias(const bf16* __restrict__ A, const bf16* __restrict__ Bm,
               const float* __restrict__ b1, const float* __restrict__ b2,
               float* __restrict__ C, int M, int N, int K) {
    const int lane = threadIdx.x;
    const int tn = N >> 6;
    const int bm = blockIdx.x / tn, bn = blockIdx.x - bm * tn;
    const int m0 = bm << 6, n0 = bn << 6;
    const int fr = lane & 15, kq = (lane >> 4) << 3;
    f32x4 acc[4][4];
#pragma unroll
    for (int i = 0; i < 4; i++)
#pragma unroll
        for (int j = 0; j < 4; j++) acc[i][j] = (f32x4){0.f, 0.f, 0.f, 0.f};
    const bf16* Ap = A + (size_t)(m0 + fr) * K + kq;
    const bf16* Bp = Bm + (size_t)(n0 + fr) * K + kq;
    for (int k = 0; k < K; k += 32) {
        short8 af[4], bfr[4];
#pragma unroll
        for (int i = 0; i < 4; i++) af[i] = ld8(Ap + (size_t)(i * 16) * K + k);
#pragma unroll
        for (int i = 0; i < 4; i++) bfr[i] = ld8(Bp + (size_t)(i * 16) * K + k);
#pragma unroll
        for (int i = 0; i < 4; i++)
#pragma unroll
            for (int j = 0; j < 4; j++)
                acc[i][j] = mfma16(af[i], bfr[j], acc[i][j]);
    }
    const int crow = (lane >> 4) << 2, ccol = lane & 15;
#pragma unroll
    for (int j = 0; j < 4; j++) {
        const int nn = n0 + j * 16 + ccol;
        const float bias = b1[nn] + b2[nn];
#pragma unroll
        for (int i = 0; i < 4; i++) {
            const int mm = m0 + i * 16 + crow;
#pragma unroll
            for (int r = 0; r < 4; r++)
                C[(size_t)(mm + r) * N + nn] = acc[i][j][r] + bias;
        }
    }
}

// ---------- persistent LSTM scan (fence-free coherent barrier) ----------
// One launch per layer. 64 blocks x 256 threads (4 waves). Block owns 16
// hidden units; wave w = gate w. R slice pinned in 128 VGPRs; c in regs.
// y crosses the grid barrier via relaxed agent-scope atomics (sc0 sc1 -> IF$,
// coherent, no L2 flush). y staged once per block into XOR-swizzled LDS.
template <bool WRITE_OUT>
__global__ __launch_bounds__(256, 1)
void lstm_scan(const float* __restrict__ gx,   // [T,B,kG], bias included
               const bf16* __restrict__ Rbf,   // [kG,kH]
               const bf16* __restrict__ h0bf,  // [B,H]
               const float* __restrict__ c0,   // [B,H]
               bf16* __restrict__ ybuf,        // seq (L1) or ping-pong (L2)
               float* __restrict__ outf,       // fp32 out (L2) or null
               float* __restrict__ cfin,       // [B,H] final c
               unsigned* __restrict__ bar) {
    const int tid = threadIdx.x;
    const int lane = tid & 63, w = tid >> 6;
    const int u0 = blockIdx.x << 4;
    const int fr = lane & 15, kq = (lane >> 4) << 3;
    const int n = w * kH + u0;  // gate-column base

    __shared__ __align__(16) char ldsbuf[64 * 1024];
    float (*pre)[kB][17] = (float (*)[kB][17])ldsbuf;  // aliases y-LDS (synced)

    // Preload this wave's R rows into registers and PIN them (128 VGPRs).
    short8 Rf[32];
    {
        const bf16* Rp = Rbf + (size_t)(n + fr) * kH + kq;
#pragma unroll
        for (int kk = 0; kk < 32; kk++) Rf[kk] = ld8(Rp + kk * 32);
#pragma unroll
        for (int kk = 0; kk < 32; kk++) asm volatile("" : "+v"(Rf[kk]));
    }

    // Epilogue mapping: row = tid>>3 (0..31), col pair = (tid&7)*2.
    const int erow = tid >> 3, ecp = (tid & 7) << 1;
    const int ubase = u0 + ecp;
    float creg0 = c0[(size_t)erow * kH + ubase];
    float creg1 = c0[(size_t)erow * kH + ubase + 1];

    const int crow = (lane >> 4) << 2, ccol = lane & 15;
    // LDS fragment read offsets (bytes, pre-swizzle); same XOR for row, row+16.
    const int a0base = fr * 2048 + kq * 2;
    const int a1base = (16 + fr) * 2048 + kq * 2;
    const int aswz = (fr & 7) << 4;

#pragma unroll 1
    for (int t = 0; t < kT; t++) {
        const unsigned* ysrc_dw = (const unsigned*)(
            (t == 0) ? h0bf
                     : (WRITE_OUT ? ybuf + (size_t)((t - 1) & 1) * kBH
                                  : ybuf + (size_t)(t - 1) * kBH));
        // Stage y (32x1024 bf16 = 64KB) into swizzled LDS via coherent loads.
#pragma unroll 16
        for (int j = 0; j < 64; j++) {
            const int d = tid + 256 * j;
            const unsigned v = __hip_atomic_load(
                ysrc_dw + d, __ATOMIC_RELAXED, __HIP_MEMORY_SCOPE_AGENT);
            const int byte = d << 2;
            *(unsigned*)(ldsbuf + (byte ^ (((byte >> 11) & 7) << 4))) = v;
        }
        // gx prefetch (plain loads; gx is written before launch, L2-cacheable).
        const float* gx_t = gx + (size_t)t * (kB * kG);
        float e0[4], e1[4];
#pragma unroll
        for (int r = 0; r < 4; r++) {
            e0[r] = gx_t[(size_t)(crow + r) * kG + n + ccol];
            e1[r] = gx_t[(size_t)(crow + r + 16) * kG + n + ccol];
        }
        __syncthreads();  // staging complete
        // Recurrent GEMM: y_{t-1}[32,1024] @ R[n..n+15,:]^T, A from LDS, B regs.
        f32x4 a0e = {0.f, 0.f, 0.f, 0.f}, a0o = {0.f, 0.f, 0.f, 0.f};
        f32x4 a1e = {0.f, 0.f, 0.f, 0.f}, a1o = {0.f, 0.f, 0.f, 0.f};
#pragma unroll
        for (int kk = 0; kk < 32; kk += 2) {
            const short8 x0 = *(const short8*)(ldsbuf + ((a0base + kk * 64) ^ aswz));
            const short8 x1 = *(const short8*)(ldsbuf + ((a1base + kk * 64) ^ aswz));
            const short8 x2 = *(const short8*)(ldsbuf + ((a0base + kk * 64 + 64) ^ aswz));
            const short8 x3 = *(const short8*)(ldsbuf + ((a1base + kk * 64 + 64) ^ aswz));
            a0e = mfma16(x0, Rf[kk], a0e);
            a1e = mfma16(x1, Rf[kk], a1e);
            a0o = mfma16(x2, Rf[kk + 1], a0o);
            a1o = mfma16(x3, Rf[kk + 1], a1o);
        }
        const f32x4 acc0 = a0e + a0o, acc1 = a1e + a1o;
        __syncthreads();  // all LDS y reads done; safe to alias pre[] over it
#pragma unroll
        for (int r = 0; r < 4; r++) {
            pre[w][crow + r][ccol] = acc0[r] + e0[r];
            pre[w][crow + r + 16][ccol] = acc1[r] + e1[r];
        }
        __syncthreads();
        // Fused gates + c/y update (2 adjacent cells per thread).
        {
            const float pi0 = pre[0][erow][ecp], pi1 = pre[0][erow][ecp + 1];
            const float pf0 = pre[1][erow][ecp], pf1 = pre[1][erow][ecp + 1];
            const float pg0 = pre[2][erow][ecp], pg1 = pre[2][erow][ecp + 1];
            const float po0 = pre[3][erow][ecp], po1 = pre[3][erow][ecp + 1];
            creg0 = sigmoidf(pf0) * creg0 + sigmoidf(pi0) * tanhf(pg0);
            creg1 = sigmoidf(pf1) * creg1 + sigmoidf(pi1) * tanhf(pg1);
            const float y0 = sigmoidf(po0) * tanhf(creg0);
            const float y1v = sigmoidf(po1) * tanhf(creg1);
            union { bf16 b[2]; unsigned u; } pk;
            pk.b[0] = __float2bfloat16(y0);
            pk.b[1] = __float2bfloat16(y1v);
            bf16* yd = WRITE_OUT ? ybuf + (size_t)(t & 1) * kBH
                                 : ybuf + (size_t)t * kBH;
            __hip_atomic_store((unsigned*)(yd + (size_t)erow * kH + ubase),
                               pk.u, __ATOMIC_RELAXED, __HIP_MEMORY_SCOPE_AGENT);
            if (WRITE_OUT) {
                float* od = outf + (size_t)t * kBH + (size_t)erow * kH + ubase;
                od[0] = y0;
                od[1] = y1v;
            }
        }
        if (t != kT - 1) {
            // Fence-free grid barrier: own stores globally visible (vmcnt 0),
            // then counter rendezvous at the coherence point.
            asm volatile("s_waitcnt vmcnt(0)" ::: "memory");
            __syncthreads();
            if (tid == 0) {
                __hip_atomic_fetch_add(bar, 1u, __ATOMIC_RELAXED,
                                       __HIP_MEMORY_SCOPE_AGENT);
                const unsigned tgt = (unsigned)kNB * (unsigned)(t + 1);
                while (__hip_atomic_load(bar, __ATOMIC_RELAXED,
                                         __HIP_MEMORY_SCOPE_AGENT) < tgt)
                    __builtin_amdgcn_s_sleep(4);
            }
            __syncthreads();
        }
    }
    cfin[(size_t)erow * kH + ubase] = creg0;
    cfin[(size_t)erow * kH + ubase + 1] = creg1;
}

// ---------- legacy per-step kernel (Path B fallback) ----------
template <bool FUSED>
__global__ __launch_bounds__(256)
void lstm_step_mfma(const float* __restrict__ gx,
                    const bf16* __restrict__ xbf,
                    const bf16* __restrict__ Wbf,
                    const float* __restrict__ b1,
                    const float* __restrict__ b2,
                    const bf16* __restrict__ Rbf,
                    const bf16* __restrict__ ysrc,
                    bf16* __restrict__ ydst_bf,
                    float* __restrict__ ydst_f,
                    float* __restrict__ cst) {
    const int lane = threadIdx.x & 63, w = threadIdx.x >> 6;
    const int u0 = blockIdx.x << 4;
    const int fr = lane & 15, kq = (lane >> 4) << 3;
    const int n = w * kH + u0;
    f32x4 acc0 = {0.f, 0.f, 0.f, 0.f}, acc1 = {0.f, 0.f, 0.f, 0.f};
    {
        const bf16* Bp = Rbf + (size_t)(n + fr) * kH + kq;
        const bf16* A0 = ysrc + (size_t)fr * kH + kq;
        const bf16* A1 = ysrc + (size_t)(16 + fr) * kH + kq;
#pragma unroll 4
        for (int k = 0; k < kH; k += 32) {
            short8 bfrag = ld8(Bp + k);
            short8 a0 = ld8(A0 + k);
            short8 a1 = ld8(A1 + k);
            acc0 = mfma16(a0, bfrag, acc0);
            acc1 = mfma16(a1, bfrag, acc1);
        }
    }
    if (FUSED) {
        const bf16* Bp = Wbf + (size_t)(n + fr) * kIN + kq;
        const bf16* A0 = xbf + (size_t)fr * kIN + kq;
        const bf16* A1 = xbf + (size_t)(16 + fr) * kIN + kq;
#pragma unroll 4
        for (int k = 0; k < kIN; k += 32) {
            short8 bfrag = ld8(Bp + k);
            short8 a0 = ld8(A0 + k);
            short8 a1 = ld8(A1 + k);
            acc0 = mfma16(a0, bfrag, acc0);
            acc1 = mfma16(a1, bfrag, acc1);
        }
    }
    __shared__ float pre[4][kB][16];
    const int crow = (lane >> 4) << 2, ccol = lane & 15;
#pragma unroll
    for (int r = 0; r < 4; r++) {
        const int b = crow + r;
        float e0, e1;
        if (FUSED) {
            const float bias = b1[n + ccol] + b2[n + ccol];
            e0 = bias; e1 = bias;
        } else {
            e0 = gx[(size_t)b * kG + n + ccol];
            e1 = gx[(size_t)(b + 16) * kG + n + ccol];
        }
        pre[w][b][ccol] = acc0[r] + e0;
        pre[w][b + 16][ccol] = acc1[r] + e1;
    }
    __syncthreads();
    for (int idx = threadIdx.x; idx < kB * 16; idx += 256) {
        const int b = idx >> 4, col = idx & 15;
        const int u = u0 + col;
        const float iv = sigmoidf(pre[0][b][col]);
        const float fv = sigmoidf(pre[1][b][col]);
        const float gv = tanhf(pre[2][b][col]);
        const float ov = sigmoidf(pre[3][b][col]);
        const size_t off = (size_t)b * kH + u;
        const float c = fv * cst[off] + iv * gv;
        const float y = ov * tanhf(c);
        cst[off] = c;
        ydst_bf[off] = __float2bfloat16(y);
        if (ydst_f) ydst_f[off] = y;
    }
}

__global__ void finalize_bf(const bf16* __restrict__ y1last,
                            const float* __restrict__ cst,
                            float* __restrict__ out) {
    const int idx = blockIdx.x * blockDim.x + threadIdx.x;
    if (idx >= 2 * kBH) return;
    const float hv = (idx < kBH)
        ? __bfloat162float(y1last[idx])
        : out[(size_t)(kT - 1) * kBH + (idx - kBH)];
    out[(size_t)kT * kBH + idx] = hv;
    out[(size_t)kT * kBH + 2 * kBH + idx] = cst[idx];
}

// ---------- round-9 naive fallback (proven correct, 512 KB ws) ----------
__global__ __launch_bounds__(128)
void lstm_step_naive(const float* __restrict__ xA, const float* __restrict__ Wm,
                     const float* __restrict__ bWv, const float* __restrict__ bRv,
                     const float* __restrict__ Rm, const float* __restrict__ ysrc,
                     float* __restrict__ ydst, float* __restrict__ cst) {
    const int tid = threadIdx.x;
    const int b0 = (blockIdx.x & 1) << 4;
    const int bl = tid & 15;
    const int b  = b0 + bl;
    const int u  = ((blockIdx.x >> 1) << 3) + (tid >> 4);
    __shared__ float As[16][129];
    float acc[4] = {0.f, 0.f, 0.f, 0.f};
    const float* wrow[4];
#pragma unroll
    for (int g = 0; g < 4; g++) wrow[g] = Wm + (size_t)(g * kH + u) * 1024;
    for (int k0 = 0; k0 < 1024; k0 += 128) {
        __syncthreads();
        for (int i = tid; i < 16 * 128; i += 128)
            As[i >> 7][i & 127] = xA[(size_t)(b0 + (i >> 7)) * 1024 + k0 + (i & 127)];
        __syncthreads();
#pragma unroll 4
        for (int k = 0; k < 128; k += 4) {
            const float a0 = As[bl][k], a1 = As[bl][k + 1];
            const float a2 = As[bl][k + 2], a3 = As[bl][k + 3];
#pragma unroll
            for (int g = 0; g < 4; g++) {
                const float4 w4 = *reinterpret_cast<const float4*>(wrow[g] + k0 + k);
                acc[g] += a0 * w4.x + a1 * w4.y + a2 * w4.z + a3 * w4.w;
            }
        }
    }
#pragma unroll
    for (int g = 0; g < 4; g++) wrow[g] = Rm + (size_t)(g * kH + u) * 1024;
    for (int k0 = 0; k0 < 1024; k0 += 128) {
        __syncthreads();
        for (int i = tid; i < 16 * 128; i += 128)
            As[i >> 7][i & 127] = ysrc[(size_t)(b0 + (i >> 7)) * 1024 + k0 + (i & 127)];
        __syncthreads();
#pragma unroll 4
        for (int k = 0; k < 128; k += 4) {
            const float a0 = As[bl][k], a1 = As[bl][k + 1];
            const float a2 = As[bl][k + 2], a3 = As[bl][k + 3];
#pragma unroll
            for (int g = 0; g < 4; g++) {
                const float4 w4 = *reinterpret_cast<const float4*>(wrow[g] + k0 + k);
                acc[g] += a0 * w4.x + a1 * w4.y + a2 * w4.z + a3 * w4.w;
            }
        }
    }
#pragma unroll
    for (int g = 0; g < 4; g++) acc[g] += bWv[g * kH + u] + bRv[g * kH + u];
    const float iv = sigmoidf(acc[0]);
    const float fv = sigmoidf(acc[1]);
    const float gv = tanhf(acc[2]);
    const float ov = sigmoidf(acc[3]);
    const size_t off = (size_t)b * kH + u;
    const float c = fv * cst[off] + iv * gv;
    const float y = ov * tanhf(c);
    cst[off] = c;
    ydst[off] = y;
}

__global__ void finalize_f32(const float* __restrict__ y1last,
                             const float* __restrict__ cst,
                             float* __restrict__ out) {
    const int idx = blockIdx.x * blockDim.x + threadIdx.x;
    if (idx >= 2 * kBH) return;
    const float hv = (idx < kBH) ? y1last[idx]
                                 : out[(size_t)(kT - 1) * kBH + (idx - kBH)];
    out[(size_t)kT * kBH + idx] = hv;
    out[(size_t)kT * kBH + 2 * kBH + idx] = cst[idx];
}

extern "C" void kernel_launch(void* const* d_in, const int* in_sizes, int n_in,
                              void* d_out, int out_size, void* d_ws, size_t ws_size,
                              hipStream_t stream) {
    (void)in_sizes; (void)n_in; (void)out_size;
    const float* x   = (const float*)d_in[0];
    const float* h0  = (const float*)d_in[1];
    const float* c0  = (const float*)d_in[2];
    const float* W0  = (const float*)d_in[3];
    const float* R0  = (const float*)d_in[4];
    const float* bW0 = (const float*)d_in[5];
    const float* bR0 = (const float*)d_in[6];
    const float* W1  = (const float*)d_in[7];
    const float* R1  = (const float*)d_in[8];
    const float* bW1 = (const float*)d_in[9];
    const float* bR1 = (const float*)d_in[10];
    float* out = (float*)d_out;
    char* wsp = (char*)d_ws;

    const size_t gxB  = (size_t)kT * kB * kG * 4;   // 134,217,728
    const size_t xbfB = (size_t)kT * kBH * 2;       //  16,777,216
    const size_t wB   = (size_t)kG * kH * 2;        //   8,388,608 each
    const size_t hbfB = 2 * (size_t)kBH * 2;        //     131,072
    const size_t ppB  = 2 * (size_t)kBH * 2;        //     131,072
    const size_t cstB = 2 * (size_t)kBH * 4;        //     262,144
    const size_t barB = 256;                        // L1 uses [0], L2 uses [16]
    const size_t needA = gxB + 2 * xbfB + 4 * wB + hbfB + ppB + cstB + barB;
    const size_t needB = xbfB + 4 * wB + hbfB + 2 * ppB + cstB;

    const dim3 cvB(256), stB(256), stG(kNB), fiG((2 * kBH + 255) / 256);

    if (ws_size >= needA) {
        // ---- Path A: gx precompute + persistent scan per layer ----
        float* gx    = (float*)wsp;
        bf16*  xbf   = (bf16*)(wsp + gxB);
        bf16*  y1seq = (bf16*)(wsp + gxB + xbfB);
        bf16*  Wb0   = (bf16*)(wsp + gxB + 2 * xbfB);
        bf16*  Rb0   = (bf16*)((char*)Wb0 + wB);
        bf16*  Wb1   = (bf16*)((char*)Wb0 + 2 * wB);
        bf16*  Rb1   = (bf16*)((char*)Wb0 + 3 * wB);
        bf16*  hbf   = (bf16*)((char*)Wb0 + 4 * wB);
        bf16*  y2pp  = (bf16*)((char*)hbf + hbfB);
        float* cst   = (float*)((char*)y2pp + ppB);
        unsigned* bar = (unsigned*)((char*)cst + cstB);

        hipMemsetAsync(bar, 0, barB, stream);
        cvt_f32_bf16<<<dim3(1024), cvB, 0, stream>>>(x, xbf, kT * kBH);
        cvt_f32_bf16<<<dim3(1024), cvB, 0, stream>>>(W0, Wb0, kG * kH);
        cvt_f32_bf16<<<dim3(1024), cvB, 0, stream>>>(R0, Rb0, kG * kH);
        cvt_f32_bf16<<<dim3(1024), cvB, 0, stream>>>(W1, Wb1, kG * kH);
        cvt_f32_bf16<<<dim3(1024), cvB, 0, stream>>>(R1, Rb1, kG * kH);
        cvt_f32_bf16<<<dim3(64), cvB, 0, stream>>>(h0, hbf, 2 * kBH);

        gemm_bias<<<dim3((kT * kB / 64) * (kG / 64)), dim3(64), 0, stream>>>(
            xbf, Wb0, bW0, bR0, gx, kT * kB, kG, kIN);
        lstm_scan<false><<<stG, stB, 0, stream>>>(
            gx, Rb0, hbf, c0, y1seq, nullptr, cst, bar);
        gemm_bias<<<dim3((kT * kB / 64) * (kG / 64)), dim3(64), 0, stream>>>(
            y1seq, Wb1, bW1, bR1, gx, kT * kB, kG, kH);
        lstm_scan<true><<<stG, stB, 0, stream>>>(
            gx, Rb1, hbf + kBH, c0 + kBH, y2pp, out, cst + kBH, bar + 16);
        finalize_bf<<<fiG, dim3(256), 0, stream>>>(
            y1seq + (size_t)(kT - 1) * kBH, cst, out);
    } else if (ws_size >= needB) {
        // ---- Path B: fused W-matmul per step ----
        bf16*  xbf  = (bf16*)wsp;
        bf16*  Wb0  = (bf16*)(wsp + xbfB);
        bf16*  Rb0  = (bf16*)((char*)Wb0 + wB);
        bf16*  Wb1  = (bf16*)((char*)Wb0 + 2 * wB);
        bf16*  Rb1  = (bf16*)((char*)Wb0 + 3 * wB);
        bf16*  hbf  = (bf16*)((char*)Wb0 + 4 * wB);
        bf16*  y1pp = (bf16*)((char*)hbf + hbfB);
        bf16*  y2pp = (bf16*)((char*)y1pp + ppB);
        float* cst  = (float*)((char*)y2pp + ppB);

        cvt_f32_bf16<<<dim3(1024), cvB, 0, stream>>>(x, xbf, kT * kBH);
        cvt_f32_bf16<<<dim3(1024), cvB, 0, stream>>>(W0, Wb0, kG * kH);
        cvt_f32_bf16<<<dim3(1024), cvB, 0, stream>>>(R0, Rb0, kG * kH);
        cvt_f32_bf16<<<dim3(1024), cvB, 0, stream>>>(W1, Wb1, kG * kH);
        cvt_f32_bf16<<<dim3(1024), cvB, 0, stream>>>(R1, Rb1, kG * kH);
        cvt_f32_bf16<<<dim3(64), cvB, 0, stream>>>(h0, hbf, 2 * kBH);
        hipMemcpyAsync(cst, c0, cstB, hipMemcpyDeviceToDevice, stream);

        for (int t = 0; t < kT; t++) {
            const bf16* ys0 = t ? y1pp + (size_t)((t - 1) & 1) * kBH : hbf;
            bf16* y1t = y1pp + (size_t)(t & 1) * kBH;
            lstm_step_mfma<true><<<stG, stB, 0, stream>>>(
                nullptr, xbf + (size_t)t * kBH, Wb0, bW0, bR0,
                Rb0, ys0, y1t, nullptr, cst);
            const bf16* ys1 = t ? y2pp + (size_t)((t - 1) & 1) * kBH : hbf + kBH;
            lstm_step_mfma<true><<<stG, stB, 0, stream>>>(
                nullptr, y1t, Wb1, bW1, bR1,
                Rb1, ys1, y2pp + (size_t)(t & 1) * kBH,
                out + (size_t)t * kBH, cst + kBH);
        }
        finalize_bf<<<fiG, dim3(256), 0, stream>>>(
            y1pp + (size_t)((kT - 1) & 1) * kBH, cst, out);
    } else {
        // ---- Path C: round-9 naive fp32 (proven) ----
        float* y1pp = (float*)wsp;
        float* cst  = y1pp + 2 * (size_t)kBH;
        hipMemcpyAsync(cst, c0, cstB, hipMemcpyDeviceToDevice, stream);
        for (int t = 0; t < kT; t++) {
            const float* ys0 = t ? y1pp + (size_t)((t - 1) & 1) * kBH : h0;
            float* y1t = y1pp + (size_t)(t & 1) * kBH;
            lstm_step_naive<<<dim3(256), dim3(128), 0, stream>>>(
                x + (size_t)t * kB * kIN, W0, bW0, bR0, R0, ys0, y1t, cst);
            const float* ys1 = t ? out + (size_t)(t - 1) * kBH : h0 + kBH;
            lstm_step_naive<<<dim3(256), dim3(128), 0, stream>>>(
                y1t, W1, bW1, bR1, R1, ys1, out + (size_t)t * kBH, cst + kBH);
        }
        finalize_f32<<<fiG, dim3(256), 0, stream>>>(
            y1pp + (size_t)((kT - 1) & 1) * kBH, cst, out);
    }
}

// Round 9
// 4583.050 us; speedup vs baseline: 2.1357x; 2.1357x over previous
//
#include <hip/hip_runtime.h>
#include <hip/hip_bf16.h>

using bf16 = __hip_bfloat16;
typedef __attribute__((ext_vector_type(8))) short short8;   // 8 bf16 = 16B
typedef __attribute__((ext_vector_type(4))) float f32x4;

constexpr int kT = 256, kB = 32, kIN = 1024, kH = 1024, kG = 4096;
constexpr int kBH = kB * kH;  // 32768
constexpr int kNB = kH / 16;  // 64 blocks per scan

__device__ inline f32x4 mfma16(short8 a, short8 b, f32x4 c) {
    return __builtin_amdgcn_mfma_f32_16x16x32_bf16(a, b, c, 0, 0, 0);
}
__device__ inline short8 ld8(const bf16* p) {
    return *reinterpret_cast<const short8*>(p);
}
__device__ inline float sigmoidf(float x) { return 1.f / (1.f + expf(-x)); }

// ---------- prep: fp32 -> bf16 ----------
__global__ void cvt_f32_bf16(const float* __restrict__ in,
                             bf16* __restrict__ outp, int n) {
    for (int i = blockIdx.x * blockDim.x + threadIdx.x; i < n;
         i += gridDim.x * blockDim.x)
        outp[i] = __float2bfloat16(in[i]);
}

// ---------- big GEMM: C[M,N] f32 = A[M,K]bf16 @ Bm[N,K]^T bf16 + b1+b2 ----------
__global__ __launch_bounds__(64)
void gemm_bias(const bf16* __restrict__ A, const bf16* __restrict__ Bm,
               const float* __restrict__ b1, const float* __restrict__ b2,
               float* __restrict__ C, int M, int N, int K) {
    const int lane = threadIdx.x;
    const int tn = N >> 6;
    const int bm = blockIdx.x / tn, bn = blockIdx.x - bm * tn;
    const int m0 = bm << 6, n0 = bn << 6;
    const int fr = lane & 15, kq = (lane >> 4) << 3;
    f32x4 acc[4][4];
#pragma unroll
    for (int i = 0; i < 4; i++)
#pragma unroll
        for (int j = 0; j < 4; j++) acc[i][j] = (f32x4){0.f, 0.f, 0.f, 0.f};
    const bf16* Ap = A + (size_t)(m0 + fr) * K + kq;
    const bf16* Bp = Bm + (size_t)(n0 + fr) * K + kq;
    for (int k = 0; k < K; k += 32) {
        short8 af[4], bfr[4];
#pragma unroll
        for (int i = 0; i < 4; i++) af[i] = ld8(Ap + (size_t)(i * 16) * K + k);
#pragma unroll
        for (int i = 0; i < 4; i++) bfr[i] = ld8(Bp + (size_t)(i * 16) * K + k);
#pragma unroll
        for (int i = 0; i < 4; i++)
#pragma unroll
            for (int j = 0; j < 4; j++)
                acc[i][j] = mfma16(af[i], bfr[j], acc[i][j]);
    }
    const int crow = (lane >> 4) << 2, ccol = lane & 15;
#pragma unroll
    for (int j = 0; j < 4; j++) {
        const int nn = n0 + j * 16 + ccol;
        const float bias = b1[nn] + b2[nn];
#pragma unroll
        for (int i = 0; i < 4; i++) {
            const int mm = m0 + i * 16 + crow;
#pragma unroll
            for (int r = 0; r < 4; r++)
                C[(size_t)(mm + r) * N + nn] = acc[i][j][r] + bias;
        }
    }
}

// ---------- persistent LSTM scan v2: 16 waves/block, K-split 4 ----------
// 64 blocks x 1024 threads (16 waves = 4/SIMD -> latency hiding).
// Wave w: gate g=w&3, K-segment s=w>>2 (256 wide). R slice = 8 short8 = 32 VGPR.
// Per round: stage y (64KB, swizzled LDS) -> 16 MFMAs/wave -> partial sums in
// LDS (aliased over y) -> tid<256 reduce + gates + c/y update.
// y crosses the grid barrier via relaxed agent-scope atomics (coherent, no
// L2 flush; verified correct in round 7).
template <bool WRITE_OUT>
__global__ __launch_bounds__(1024, 1)
void lstm_scan(const float* __restrict__ gx,   // [T,B,kG], bias included
               const bf16* __restrict__ Rbf,   // [kG,kH]
               const bf16* __restrict__ h0bf,  // [B,H]
               const float* __restrict__ c0,   // [B,H]
               bf16* __restrict__ ybuf,        // seq (L1) or ping-pong (L2)
               float* __restrict__ outf,       // fp32 out (L2) or null
               float* __restrict__ cfin,       // [B,H] final c
               unsigned* __restrict__ bar) {
    const int tid = threadIdx.x;
    const int lane = tid & 63, w = tid >> 6;
    const int g = w & 3, s = w >> 2;       // gate, K-segment
    const int u0 = blockIdx.x << 4;
    const int fr = lane & 15;
    const int n = g * kH + u0;             // gate-column base

    __shared__ __align__(16) char ldsbuf[64 * 1024];
    float* pall = (float*)ldsbuf;          // aliased partials (synced)

    // R fragments for (gate g, seg s): 8 x short8 = 32 VGPRs, trivially resident.
    short8 Rf[8];
    {
        const bf16* Rp = Rbf + (size_t)(n + fr) * kH + s * 256 + (lane >> 4) * 8;
#pragma unroll
        for (int kk = 0; kk < 8; kk++) Rf[kk] = ld8(Rp + kk * 32);
    }

    // Epilogue ownership (tid<256): b=tid>>3, col pair u0+(tid&7)*2.
    const int eb = tid >> 3, ecp = (tid & 7) << 1;
    float creg0 = 0.f, creg1 = 0.f;
    if (tid < 256) {
        creg0 = c0[(size_t)eb * kH + u0 + ecp];
        creg1 = c0[(size_t)eb * kH + u0 + ecp + 1];
    }

    const int crow = (lane >> 4) << 2, ccol = lane & 15;
    // LDS read bases (bytes): row-major y[32][2048B]; XOR-swizzle on (fr&7).
    const int cbase = s * 512 + (lane >> 4) * 16;
    const int a0base = fr * 2048 + cbase;
    const int a1base = (16 + fr) * 2048 + cbase;   // (16+fr)&7 == fr&7
    const int aswz = (fr & 7) << 4;

#pragma unroll 1
    for (int t = 0; t < kT; t++) {
        const unsigned* ysrc_dw = (const unsigned*)(
            (t == 0) ? h0bf
                     : (WRITE_OUT ? ybuf + (size_t)((t - 1) & 1) * kBH
                                  : ybuf + (size_t)(t - 1) * kBH));
        // Stage y (64KB) into swizzled LDS: 16 dwords/thread, coherent loads.
#pragma unroll 4
        for (int j = 0; j < 16; j++) {
            const int d = tid + 1024 * j;
            const unsigned v = __hip_atomic_load(
                ysrc_dw + d, __ATOMIC_RELAXED, __HIP_MEMORY_SCOPE_AGENT);
            const int byte = d << 2;
            *(unsigned*)(ldsbuf + (byte ^ (((byte >> 11) & 7) << 4))) = v;
        }
        // gx prefetch for the epilogue (in flight across the MFMA phase).
        float e[4][2];
        if (tid < 256) {
            const float* gp = gx + (size_t)t * (kB * kG) + (size_t)eb * kG
                              + u0 + ecp;
#pragma unroll
            for (int gg = 0; gg < 4; gg++) {
                e[gg][0] = gp[gg * kH];
                e[gg][1] = gp[gg * kH + 1];
            }
        }
        __syncthreads();  // staging complete
        // Partial recurrent GEMM over this wave's K-segment.
        f32x4 acc0 = {0.f, 0.f, 0.f, 0.f}, acc1 = {0.f, 0.f, 0.f, 0.f};
#pragma unroll
        for (int kk = 0; kk < 8; kk++) {
            const short8 x0 = *(const short8*)(ldsbuf + ((a0base + kk * 64) ^ aswz));
            const short8 x1 = *(const short8*)(ldsbuf + ((a1base + kk * 64) ^ aswz));
            acc0 = mfma16(x0, Rf[kk], acc0);
            acc1 = mfma16(x1, Rf[kk], acc1);
        }
        __syncthreads();  // all y LDS reads done; safe to alias pall
#pragma unroll
        for (int r = 0; r < 4; r++) {
            pall[(((s * 4 + g) * 32) + crow + r) * 17 + ccol] = acc0[r];
            pall[(((s * 4 + g) * 32) + crow + r + 16) * 17 + ccol] = acc1[r];
        }
        __syncthreads();
        // Reduce 4 K-segments + gates + c/y update (2 adjacent cells/thread).
        if (tid < 256) {
            float v[4][2];
#pragma unroll
            for (int gg = 0; gg < 4; gg++) {
                float s0 = 0.f, s1 = 0.f;
#pragma unroll
                for (int ss = 0; ss < 4; ss++) {
                    const int base = ((ss * 4 + gg) * 32 + eb) * 17 + ecp;
                    s0 += pall[base];
                    s1 += pall[base + 1];
                }
                v[gg][0] = s0 + e[gg][0];
                v[gg][1] = s1 + e[gg][1];
            }
            creg0 = sigmoidf(v[1][0]) * creg0 + sigmoidf(v[0][0]) * tanhf(v[2][0]);
            creg1 = sigmoidf(v[1][1]) * creg1 + sigmoidf(v[0][1]) * tanhf(v[2][1]);
            const float y0 = sigmoidf(v[3][0]) * tanhf(creg0);
            const float y1v = sigmoidf(v[3][1]) * tanhf(creg1);
            union { bf16 b[2]; unsigned u; } pk;
            pk.b[0] = __float2bfloat16(y0);
            pk.b[1] = __float2bfloat16(y1v);
            bf16* yd = WRITE_OUT ? ybuf + (size_t)(t & 1) * kBH
                                 : ybuf + (size_t)t * kBH;
            __hip_atomic_store((unsigned*)(yd + (size_t)eb * kH + u0 + ecp),
                               pk.u, __ATOMIC_RELAXED, __HIP_MEMORY_SCOPE_AGENT);
            if (WRITE_OUT) {
                float* od = outf + (size_t)t * kBH + (size_t)eb * kH + u0 + ecp;
                od[0] = y0;
                od[1] = y1v;
            }
        }
        if (t != kT - 1) {
            // Fence-free grid barrier (verified r7): drain own stores, rendezvous.
            asm volatile("s_waitcnt vmcnt(0)" ::: "memory");
            __syncthreads();
            if (tid == 0) {
                __hip_atomic_fetch_add(bar, 1u, __ATOMIC_RELAXED,
                                       __HIP_MEMORY_SCOPE_AGENT);
                const unsigned tgt = (unsigned)kNB * (unsigned)(t + 1);
                while (__hip_atomic_load(bar, __ATOMIC_RELAXED,
                                         __HIP_MEMORY_SCOPE_AGENT) < tgt)
                    __builtin_amdgcn_s_sleep(4);
            }
            __syncthreads();
        }
    }
    if (tid < 256) {
        cfin[(size_t)eb * kH + u0 + ecp] = creg0;
        cfin[(size_t)eb * kH + u0 + ecp + 1] = creg1;
    }
}

// ---------- legacy per-step kernel (Path B fallback) ----------
template <bool FUSED>
__global__ __launch_bounds__(256)
void lstm_step_mfma(const float* __restrict__ gx,
                    const bf16* __restrict__ xbf,
                    const bf16* __restrict__ Wbf,
                    const float* __restrict__ b1,
                    const float* __restrict__ b2,
                    const bf16* __restrict__ Rbf,
                    const bf16* __restrict__ ysrc,
                    bf16* __restrict__ ydst_bf,
                    float* __restrict__ ydst_f,
                    float* __restrict__ cst) {
    const int lane = threadIdx.x & 63, w = threadIdx.x >> 6;
    const int u0 = blockIdx.x << 4;
    const int fr = lane & 15, kq = (lane >> 4) << 3;
    const int n = w * kH + u0;
    f32x4 acc0 = {0.f, 0.f, 0.f, 0.f}, acc1 = {0.f, 0.f, 0.f, 0.f};
    {
        const bf16* Bp = Rbf + (size_t)(n + fr) * kH + kq;
        const bf16* A0 = ysrc + (size_t)fr * kH + kq;
        const bf16* A1 = ysrc + (size_t)(16 + fr) * kH + kq;
#pragma unroll 4
        for (int k = 0; k < kH; k += 32) {
            short8 bfrag = ld8(Bp + k);
            short8 a0 = ld8(A0 + k);
            short8 a1 = ld8(A1 + k);
            acc0 = mfma16(a0, bfrag, acc0);
            acc1 = mfma16(a1, bfrag, acc1);
        }
    }
    if (FUSED) {
        const bf16* Bp = Wbf + (size_t)(n + fr) * kIN + kq;
        const bf16* A0 = xbf + (size_t)fr * kIN + kq;
        const bf16* A1 = xbf + (size_t)(16 + fr) * kIN + kq;
#pragma unroll 4
        for (int k = 0; k < kIN; k += 32) {
            short8 bfrag = ld8(Bp + k);
            short8 a0 = ld8(A0 + k);
            short8 a1 = ld8(A1 + k);
            acc0 = mfma16(a0, bfrag, acc0);
            acc1 = mfma16(a1, bfrag, acc1);
        }
    }
    __shared__ float pre[4][kB][16];
    const int crow = (lane >> 4) << 2, ccol = lane & 15;
#pragma unroll
    for (int r = 0; r < 4; r++) {
        const int b = crow + r;
        float e0, e1;
        if (FUSED) {
            const float bias = b1[n + ccol] + b2[n + ccol];
            e0 = bias; e1 = bias;
        } else {
            e0 = gx[(size_t)b * kG + n + ccol];
            e1 = gx[(size_t)(b + 16) * kG + n + ccol];
        }
        pre[w][b][ccol] = acc0[r] + e0;
        pre[w][b + 16][ccol] = acc1[r] + e1;
    }
    __syncthreads();
    for (int idx = threadIdx.x; idx < kB * 16; idx += 256) {
        const int b = idx >> 4, col = idx & 15;
        const int u = u0 + col;
        const float iv = sigmoidf(pre[0][b][col]);
        const float fv = sigmoidf(pre[1][b][col]);
        const float gv = tanhf(pre[2][b][col]);
        const float ov = sigmoidf(pre[3][b][col]);
        const size_t off = (size_t)b * kH + u;
        const float c = fv * cst[off] + iv * gv;
        const float y = ov * tanhf(c);
        cst[off] = c;
        ydst_bf[off] = __float2bfloat16(y);
        if (ydst_f) ydst_f[off] = y;
    }
}

__global__ void finalize_bf(const bf16* __restrict__ y1last,
                            const float* __restrict__ cst,
                            float* __restrict__ out) {
    const int idx = blockIdx.x * blockDim.x + threadIdx.x;
    if (idx >= 2 * kBH) return;
    const float hv = (idx < kBH)
        ? __bfloat162float(y1last[idx])
        : out[(size_t)(kT - 1) * kBH + (idx - kBH)];
    out[(size_t)kT * kBH + idx] = hv;
    out[(size_t)kT * kBH + 2 * kBH + idx] = cst[idx];
}

// ---------- round-9 naive fallback (proven correct, 512 KB ws) ----------
__global__ __launch_bounds__(128)
void lstm_step_naive(const float* __restrict__ xA, const float* __restrict__ Wm,
                     const float* __restrict__ bWv, const float* __restrict__ bRv,
                     const float* __restrict__ Rm, const float* __restrict__ ysrc,
                     float* __restrict__ ydst, float* __restrict__ cst) {
    const int tid = threadIdx.x;
    const int b0 = (blockIdx.x & 1) << 4;
    const int bl = tid & 15;
    const int b  = b0 + bl;
    const int u  = ((blockIdx.x >> 1) << 3) + (tid >> 4);
    __shared__ float As[16][129];
    float acc[4] = {0.f, 0.f, 0.f, 0.f};
    const float* wrow[4];
#pragma unroll
    for (int g = 0; g < 4; g++) wrow[g] = Wm + (size_t)(g * kH + u) * 1024;
    for (int k0 = 0; k0 < 1024; k0 += 128) {
        __syncthreads();
        for (int i = tid; i < 16 * 128; i += 128)
            As[i >> 7][i & 127] = xA[(size_t)(b0 + (i >> 7)) * 1024 + k0 + (i & 127)];
        __syncthreads();
#pragma unroll 4
        for (int k = 0; k < 128; k += 4) {
            const float a0 = As[bl][k], a1 = As[bl][k + 1];
            const float a2 = As[bl][k + 2], a3 = As[bl][k + 3];
#pragma unroll
            for (int g = 0; g < 4; g++) {
                const float4 w4 = *reinterpret_cast<const float4*>(wrow[g] + k0 + k);
                acc[g] += a0 * w4.x + a1 * w4.y + a2 * w4.z + a3 * w4.w;
            }
        }
    }
#pragma unroll
    for (int g = 0; g < 4; g++) wrow[g] = Rm + (size_t)(g * kH + u) * 1024;
    for (int k0 = 0; k0 < 1024; k0 += 128) {
        __syncthreads();
        for (int i = tid; i < 16 * 128; i += 128)
            As[i >> 7][i & 127] = ysrc[(size_t)(b0 + (i >> 7)) * 1024 + k0 + (i & 127)];
        __syncthreads();
#pragma unroll 4
        for (int k = 0; k < 128; k += 4) {
            const float a0 = As[bl][k], a1 = As[bl][k + 1];
            const float a2 = As[bl][k + 2], a3 = As[bl][k + 3];
#pragma unroll
            for (int g = 0; g < 4; g++) {
                const float4 w4 = *reinterpret_cast<const float4*>(wrow[g] + k0 + k);
                acc[g] += a0 * w4.x + a1 * w4.y + a2 * w4.z + a3 * w4.w;
            }
        }
    }
#pragma unroll
    for (int g = 0; g < 4; g++) acc[g] += bWv[g * kH + u] + bRv[g * kH + u];
    const float iv = sigmoidf(acc[0]);
    const float fv = sigmoidf(acc[1]);
    const float gv = tanhf(acc[2]);
    const float ov = sigmoidf(acc[3]);
    const size_t off = (size_t)b * kH + u;
    const float c = fv * cst[off] + iv * gv;
    const float y = ov * tanhf(c);
    cst[off] = c;
    ydst[off] = y;
}

__global__ void finalize_f32(const float* __restrict__ y1last,
                             const float* __restrict__ cst,
                             float* __restrict__ out) {
    const int idx = blockIdx.x * blockDim.x + threadIdx.x;
    if (idx >= 2 * kBH) return;
    const float hv = (idx < kBH) ? y1last[idx]
                                 : out[(size_t)(kT - 1) * kBH + (idx - kBH)];
    out[(size_t)kT * kBH + idx] = hv;
    out[(size_t)kT * kBH + 2 * kBH + idx] = cst[idx];
}

extern "C" void kernel_launch(void* const* d_in, const int* in_sizes, int n_in,
                              void* d_out, int out_size, void* d_ws, size_t ws_size,
                              hipStream_t stream) {
    (void)in_sizes; (void)n_in; (void)out_size;
    const float* x   = (const float*)d_in[0];
    const float* h0  = (const float*)d_in[1];
    const float* c0  = (const float*)d_in[2];
    const float* W0  = (const float*)d_in[3];
    const float* R0  = (const float*)d_in[4];
    const float* bW0 = (const float*)d_in[5];
    const float* bR0 = (const float*)d_in[6];
    const float* W1  = (const float*)d_in[7];
    const float* R1  = (const float*)d_in[8];
    const float* bW1 = (const float*)d_in[9];
    const float* bR1 = (const float*)d_in[10];
    float* out = (float*)d_out;
    char* wsp = (char*)d_ws;

    const size_t gxB  = (size_t)kT * kB * kG * 4;   // 134,217,728
    const size_t xbfB = (size_t)kT * kBH * 2;       //  16,777,216
    const size_t wB   = (size_t)kG * kH * 2;        //   8,388,608 each
    const size_t hbfB = 2 * (size_t)kBH * 2;        //     131,072
    const size_t ppB  = 2 * (size_t)kBH * 2;        //     131,072
    const size_t cstB = 2 * (size_t)kBH * 4;        //     262,144
    const size_t barB = 256;                        // L1 uses [0], L2 uses [16]
    const size_t needA = gxB + 2 * xbfB + 4 * wB + hbfB + ppB + cstB + barB;
    const size_t needB = xbfB + 4 * wB + hbfB + 2 * ppB + cstB;

    const dim3 cvB(256), stB(1024), stG(kNB), fiG((2 * kBH + 255) / 256);

    if (ws_size >= needA) {
        // ---- Path A: gx precompute + persistent scan per layer ----
        float* gx    = (float*)wsp;
        bf16*  xbf   = (bf16*)(wsp + gxB);
        bf16*  y1seq = (bf16*)(wsp + gxB + xbfB);
        bf16*  Wb0   = (bf16*)(wsp + gxB + 2 * xbfB);
        bf16*  Rb0   = (bf16*)((char*)Wb0 + wB);
        bf16*  Wb1   = (bf16*)((char*)Wb0 + 2 * wB);
        bf16*  Rb1   = (bf16*)((char*)Wb0 + 3 * wB);
        bf16*  hbf   = (bf16*)((char*)Wb0 + 4 * wB);
        bf16*  y2pp  = (bf16*)((char*)hbf + hbfB);
        float* cst   = (float*)((char*)y2pp + ppB);
        unsigned* bar = (unsigned*)((char*)cst + cstB);

        hipMemsetAsync(bar, 0, barB, stream);
        cvt_f32_bf16<<<dim3(1024), cvB, 0, stream>>>(x, xbf, kT * kBH);
        cvt_f32_bf16<<<dim3(1024), cvB, 0, stream>>>(W0, Wb0, kG * kH);
        cvt_f32_bf16<<<dim3(1024), cvB, 0, stream>>>(R0, Rb0, kG * kH);
        cvt_f32_bf16<<<dim3(1024), cvB, 0, stream>>>(W1, Wb1, kG * kH);
        cvt_f32_bf16<<<dim3(1024), cvB, 0, stream>>>(R1, Rb1, kG * kH);
        cvt_f32_bf16<<<dim3(64), cvB, 0, stream>>>(h0, hbf, 2 * kBH);

        gemm_bias<<<dim3((kT * kB / 64) * (kG / 64)), dim3(64), 0, stream>>>(
            xbf, Wb0, bW0, bR0, gx, kT * kB, kG, kIN);
        lstm_scan<false><<<stG, stB, 0, stream>>>(
            gx, Rb0, hbf, c0, y1seq, nullptr, cst, bar);
        gemm_bias<<<dim3((kT * kB / 64) * (kG / 64)), dim3(64), 0, stream>>>(
            y1seq, Wb1, bW1, bR1, gx, kT * kB, kG, kH);
        lstm_scan<true><<<stG, stB, 0, stream>>>(
            gx, Rb1, hbf + kBH, c0 + kBH, y2pp, out, cst + kBH, bar + 16);
        finalize_bf<<<fiG, dim3(256), 0, stream>>>(
            y1seq + (size_t)(kT - 1) * kBH, cst, out);
    } else if (ws_size >= needB) {
        // ---- Path B: fused W-matmul per step ----
        bf16*  xbf  = (bf16*)wsp;
        bf16*  Wb0  = (bf16*)(wsp + xbfB);
        bf16*  Rb0  = (bf16*)((char*)Wb0 + wB);
        bf16*  Wb1  = (bf16*)((char*)Wb0 + 2 * wB);
        bf16*  Rb1  = (bf16*)((char*)Wb0 + 3 * wB);
        bf16*  hbf  = (bf16*)((char*)Wb0 + 4 * wB);
        bf16*  y1pp = (bf16*)((char*)hbf + hbfB);
        bf16*  y2pp = (bf16*)((char*)y1pp + ppB);
        float* cst  = (float*)((char*)y2pp + ppB);

        cvt_f32_bf16<<<dim3(1024), cvB, 0, stream>>>(x, xbf, kT * kBH);
        cvt_f32_bf16<<<dim3(1024), cvB, 0, stream>>>(W0, Wb0, kG * kH);
        cvt_f32_bf16<<<dim3(1024), cvB, 0, stream>>>(R0, Rb0, kG * kH);
        cvt_f32_bf16<<<dim3(1024), cvB, 0, stream>>>(W1, Wb1, kG * kH);
        cvt_f32_bf16<<<dim3(1024), cvB, 0, stream>>>(R1, Rb1, kG * kH);
        cvt_f32_bf16<<<dim3(64), cvB, 0, stream>>>(h0, hbf, 2 * kBH);
        hipMemcpyAsync(cst, c0, cstB, hipMemcpyDeviceToDevice, stream);

        for (int t = 0; t < kT; t++) {
            const bf16* ys0 = t ? y1pp + (size_t)((t - 1) & 1) * kBH : hbf;
            bf16* y1t = y1pp + (size_t)(t & 1) * kBH;
            lstm_step_mfma<true><<<stG, dim3(256), 0, stream>>>(
                nullptr, xbf + (size_t)t * kBH, Wb0, bW0, bR0,
                Rb0, ys0, y1t, nullptr, cst);
            const bf16* ys1 = t ? y2pp + (size_t)((t - 1) & 1) * kBH : hbf + kBH;
            lstm_step_mfma<true><<<stG, dim3(256), 0, stream>>>(
                nullptr, y1t, Wb1, bW1, bR1,
                Rb1, ys1, y2pp + (size_t)(t & 1) * kBH,
                out + (size_t)t * kBH, cst + kBH);
        }
        finalize_bf<<<fiG, dim3(256), 0, stream>>>(
            y1pp + (size_t)((kT - 1) & 1) * kBH, cst, out);
    } else {
        // ---- Path C: round-9 naive fp32 (proven) ----
        float* y1pp = (float*)wsp;
        float* cst  = y1pp + 2 * (size_t)kBH;
        hipMemcpyAsync(cst, c0, cstB, hipMemcpyDeviceToDevice, stream);
        for (int t = 0; t < kT; t++) {
            const float* ys0 = t ? y1pp + (size_t)((t - 1) & 1) * kBH : h0;
            float* y1t = y1pp + (size_t)(t & 1) * kBH;
            lstm_step_naive<<<dim3(256), dim3(128), 0, stream>>>(
                x + (size_t)t * kB * kIN, W0, bW0, bR0, R0, ys0, y1t, cst);
            const float* ys1 = t ? out + (size_t)(t - 1) * kBH : h0 + kBH;
            lstm_step_naive<<<dim3(256), dim3(128), 0, stream>>>(
                y1t, W1, bW1, bR1, R1, ys1, out + (size_t)t * kBH, cst + kBH);
        }
        finalize_f32<<<fiG, dim3(256), 0, stream>>>(
            y1pp + (size_t)((kT - 1) & 1) * kBH, cst, out);
    }
}

// Round 11
// 2588.451 us; speedup vs baseline: 3.7814x; 1.7706x over previous
//
#include <hip/hip_runtime.h>
#include <hip/hip_bf16.h>

using bf16 = __hip_bfloat16;
typedef __attribute__((ext_vector_type(8))) short short8;   // 8 bf16 = 16B
typedef __attribute__((ext_vector_type(4))) float f32x4;

constexpr int kT = 256, kB = 32, kIN = 1024, kH = 1024, kG = 4096;
constexpr int kBH = kB * kH;  // 32768
constexpr int kNB = kH / 16;  // 64 blocks per layer

__device__ inline f32x4 mfma16(short8 a, short8 b, f32x4 c) {
    return __builtin_amdgcn_mfma_f32_16x16x32_bf16(a, b, c, 0, 0, 0);
}
__device__ inline short8 ld8(const bf16* p) {
    return *reinterpret_cast<const short8*>(p);
}
__device__ inline float sigmoidf(float x) { return 1.f / (1.f + expf(-x)); }

// ---------- prep: fp32 -> bf16 ----------
__global__ void cvt_f32_bf16(const float* __restrict__ in,
                             bf16* __restrict__ outp, int n) {
    for (int i = blockIdx.x * blockDim.x + threadIdx.x; i < n;
         i += gridDim.x * blockDim.x)
        outp[i] = __float2bfloat16(in[i]);
}

// ---------- big GEMM: C[M,N] f32 = A[M,K]bf16 @ Bm[N,K]^T bf16 + b1+b2 ----------
__global__ __launch_bounds__(64)
void gemm_bias(const bf16* __restrict__ A, const bf16* __restrict__ Bm,
               const float* __restrict__ b1, const float* __restrict__ b2,
               float* __restrict__ C, int M, int N, int K) {
    const int lane = threadIdx.x;
    const int tn = N >> 6;
    const int bm = blockIdx.x / tn, bn = blockIdx.x - bm * tn;
    const int m0 = bm << 6, n0 = bn << 6;
    const int fr = lane & 15, kq = (lane >> 4) << 3;
    f32x4 acc[4][4];
#pragma unroll
    for (int i = 0; i < 4; i++)
#pragma unroll
        for (int j = 0; j < 4; j++) acc[i][j] = (f32x4){0.f, 0.f, 0.f, 0.f};
    const bf16* Ap = A + (size_t)(m0 + fr) * K + kq;
    const bf16* Bp = Bm + (size_t)(n0 + fr) * K + kq;
    for (int k = 0; k < K; k += 32) {
        short8 af[4], bfr[4];
#pragma unroll
        for (int i = 0; i < 4; i++) af[i] = ld8(Ap + (size_t)(i * 16) * K + k);
#pragma unroll
        for (int i = 0; i < 4; i++) bfr[i] = ld8(Bp + (size_t)(i * 16) * K + k);
#pragma unroll
        for (int i = 0; i < 4; i++)
#pragma unroll
            for (int j = 0; j < 4; j++)
                acc[i][j] = mfma16(af[i], bfr[j], acc[i][j]);
    }
    const int crow = (lane >> 4) << 2, ccol = lane & 15;
#pragma unroll
    for (int j = 0; j < 4; j++) {
        const int nn = n0 + j * 16 + ccol;
        const float bias = b1[nn] + b2[nn];
#pragma unroll
        for (int i = 0; i < 4; i++) {
            const int mm = m0 + i * 16 + crow;
#pragma unroll
            for (int r = 0; r < 4; r++)
                C[(size_t)(mm + r) * N + nn] = acc[i][j][r] + bias;
        }
    }
}

// ---------- fused 2-layer persistent scan helpers ----------
__device__ inline void grid_wait(unsigned* cnt, unsigned tgt) {
    if (threadIdx.x == 0) {
        while (__hip_atomic_load(cnt, __ATOMIC_RELAXED,
                                 __HIP_MEMORY_SCOPE_AGENT) < tgt)
            __builtin_amdgcn_s_sleep(2);
    }
    __syncthreads();
}
__device__ inline void grid_arrive(unsigned* cnt) {
    asm volatile("s_waitcnt vmcnt(0)" ::: "memory");
    __syncthreads();
    if (threadIdx.x == 0)
        __hip_atomic_fetch_add(cnt, 1u, __ATOMIC_RELAXED,
                               __HIP_MEMORY_SCOPE_AGENT);
}
// Stage 64KB (32x1024 bf16) into XOR-swizzled LDS: 16 coherent loads batched
// into regs first (single IF$ latency), then 16 conflict-free ds_writes.
__device__ inline void stage64k(const unsigned* __restrict__ src, char* lds) {
    unsigned v[16];
#pragma unroll
    for (int j = 0; j < 16; j++)
        v[j] = __hip_atomic_load(src + threadIdx.x + 1024 * j,
                                 __ATOMIC_RELAXED, __HIP_MEMORY_SCOPE_AGENT);
#pragma unroll
    for (int j = 0; j < 16; j++) {
        const int byte = (threadIdx.x + 1024 * j) << 2;
        *(unsigned*)(lds + (byte ^ (((byte >> 11) & 7) << 4))) = v[j];
    }
}
__device__ inline void mfma_phase(const char* lds, int a0base, int a1base,
                                  int aswz, const short8* Mf,
                                  f32x4& acc0, f32x4& acc1) {
#pragma unroll
    for (int kk = 0; kk < 8; kk++) {
        const short8 x0 = *(const short8*)(lds + ((a0base + kk * 64) ^ aswz));
        const short8 x1 = *(const short8*)(lds + ((a1base + kk * 64) ^ aswz));
        acc0 = mfma16(x0, Mf[kk], acc0);
        acc1 = mfma16(x1, Mf[kk], acc1);
    }
}

// ---------- fused 2-layer pipelined scan ----------
// 128 blocks x 1024 threads (16 waves, 1 block/CU, all co-resident).
// Blocks 0..63  (A): layer 1 — gx precomputed, R0 in regs (32 VGPR/wave).
// Blocks 64..127(B): layer 2 — W1 AND R1 in regs; computes y1[t]@W1^T +
//   y2[t-1]@R1^T per round, time-sharing LDS between the two stagings.
// Pipeline: B's round t waits cntA>=64(t+1) (y1[t] ready) — lags A by ~1 round.
// Monotone counters; A never waits on B -> deadlock-free.
__global__ __launch_bounds__(1024, 1)
void lstm_fused(const float* __restrict__ gx,    // [T,B,kG] layer-1, bias incl.
                const bf16* __restrict__ R0bf,   // [kG,kH]
                const bf16* __restrict__ W1bf,   // [kG,kH]
                const bf16* __restrict__ R1bf,   // [kG,kH]
                const float* __restrict__ bW1,   // [kG]
                const float* __restrict__ bR1,   // [kG]
                const bf16* __restrict__ h0bf,   // [2,B,H]
                const float* __restrict__ c0,    // [2,B,H]
                bf16* __restrict__ y1seq,        // [T,B,H]
                bf16* __restrict__ y2pp,         // [2,B,H]
                float* __restrict__ outf,        // [T,B,H]
                float* __restrict__ cst,         // [2,B,H] final c
                unsigned* __restrict__ cntA,
                unsigned* __restrict__ cntB) {
    const int tid = threadIdx.x;
    const bool isA = blockIdx.x < kNB;
    const int bid = blockIdx.x & (kNB - 1);
    const int lane = tid & 63, w = tid >> 6;
    const int g = w & 3, s = w >> 2;       // gate, K-segment
    const int u0 = bid << 4;
    const int fr = lane & 15;
    const int n = g * kH + u0;

    __shared__ __align__(16) char ldsbuf[64 * 1024];
    float* pall = (float*)ldsbuf;          // aliased partials (synced)

    const int eb = tid >> 3, ecp = (tid & 7) << 1;
    const int crow = (lane >> 4) << 2, ccol = lane & 15;
    const int cbase = s * 512 + (lane >> 4) * 16;
    const int a0base = fr * 2048 + cbase;
    const int a1base = (16 + fr) * 2048 + cbase;   // (16+fr)&7 == fr&7
    const int aswz = (fr & 7) << 4;

    if (isA) {
        // ---------------- layer 1 ----------------
        short8 Rf[8];
        {
            const bf16* Rp = R0bf + (size_t)(n + fr) * kH + s * 256 + (lane >> 4) * 8;
#pragma unroll
            for (int kk = 0; kk < 8; kk++) Rf[kk] = ld8(Rp + kk * 32);
        }
        float creg0 = 0.f, creg1 = 0.f;
        if (tid < 256) {
            creg0 = c0[(size_t)eb * kH + u0 + ecp];
            creg1 = c0[(size_t)eb * kH + u0 + ecp + 1];
        }
#pragma unroll 1
        for (int t = 0; t < kT; t++) {
            if (t) grid_wait(cntA, (unsigned)(kNB * t));
            const unsigned* ysrc = (const unsigned*)(
                t ? y1seq + (size_t)(t - 1) * kBH : h0bf);
            stage64k(ysrc, ldsbuf);
            float e[4][2];
            if (tid < 256) {
                const float* gp = gx + (size_t)t * (kB * kG) + (size_t)eb * kG
                                  + u0 + ecp;
#pragma unroll
                for (int gg = 0; gg < 4; gg++) {
                    e[gg][0] = gp[gg * kH];
                    e[gg][1] = gp[gg * kH + 1];
                }
            }
            __syncthreads();
            f32x4 acc0 = {0.f, 0.f, 0.f, 0.f}, acc1 = {0.f, 0.f, 0.f, 0.f};
            mfma_phase(ldsbuf, a0base, a1base, aswz, Rf, acc0, acc1);
            __syncthreads();
#pragma unroll
            for (int r = 0; r < 4; r++) {
                pall[(((s * 4 + g) * 32) + crow + r) * 17 + ccol] = acc0[r];
                pall[(((s * 4 + g) * 32) + crow + r + 16) * 17 + ccol] = acc1[r];
            }
            __syncthreads();
            if (tid < 256) {
                float v[4][2];
#pragma unroll
                for (int gg = 0; gg < 4; gg++) {
                    float s0 = 0.f, s1 = 0.f;
#pragma unroll
                    for (int ss = 0; ss < 4; ss++) {
                        const int base = ((ss * 4 + gg) * 32 + eb) * 17 + ecp;
                        s0 += pall[base];
                        s1 += pall[base + 1];
                    }
                    v[gg][0] = s0 + e[gg][0];
                    v[gg][1] = s1 + e[gg][1];
                }
                creg0 = sigmoidf(v[1][0]) * creg0 + sigmoidf(v[0][0]) * tanhf(v[2][0]);
                creg1 = sigmoidf(v[1][1]) * creg1 + sigmoidf(v[0][1]) * tanhf(v[2][1]);
                const float y0 = sigmoidf(v[3][0]) * tanhf(creg0);
                const float y1v = sigmoidf(v[3][1]) * tanhf(creg1);
                union { bf16 b[2]; unsigned u; } pk;
                pk.b[0] = __float2bfloat16(y0);
                pk.b[1] = __float2bfloat16(y1v);
                __hip_atomic_store(
                    (unsigned*)(y1seq + (size_t)t * kBH + (size_t)eb * kH + u0 + ecp),
                    pk.u, __ATOMIC_RELAXED, __HIP_MEMORY_SCOPE_AGENT);
            }
            grid_arrive(cntA);  // every round — B consumes up to y1[T-1]
        }
        if (tid < 256) {
            cst[(size_t)eb * kH + u0 + ecp] = creg0;
            cst[(size_t)eb * kH + u0 + ecp + 1] = creg1;
        }
    } else {
        // ---------------- layer 2 ----------------
        short8 Wf[8], Rf[8];
        {
            const bf16* Wp = W1bf + (size_t)(n + fr) * kH + s * 256 + (lane >> 4) * 8;
            const bf16* Rp = R1bf + (size_t)(n + fr) * kH + s * 256 + (lane >> 4) * 8;
#pragma unroll
            for (int kk = 0; kk < 8; kk++) {
                Wf[kk] = ld8(Wp + kk * 32);
                Rf[kk] = ld8(Rp + kk * 32);
            }
        }
        float creg0 = 0.f, creg1 = 0.f;
        float ebias[4][2];
        if (tid < 256) {
            creg0 = c0[kBH + (size_t)eb * kH + u0 + ecp];
            creg1 = c0[kBH + (size_t)eb * kH + u0 + ecp + 1];
#pragma unroll
            for (int gg = 0; gg < 4; gg++) {
                ebias[gg][0] = bW1[gg * kH + u0 + ecp] + bR1[gg * kH + u0 + ecp];
                ebias[gg][1] = bW1[gg * kH + u0 + ecp + 1] + bR1[gg * kH + u0 + ecp + 1];
            }
        }
#pragma unroll 1
        for (int t = 0; t < kT; t++) {
            grid_wait(cntA, (unsigned)(kNB * (t + 1)));  // y1[t] ready
            stage64k((const unsigned*)(y1seq + (size_t)t * kBH), ldsbuf);
            __syncthreads();
            f32x4 acc0 = {0.f, 0.f, 0.f, 0.f}, acc1 = {0.f, 0.f, 0.f, 0.f};
            mfma_phase(ldsbuf, a0base, a1base, aswz, Wf, acc0, acc1);
            __syncthreads();                             // y1 LDS reads done
            if (t) grid_wait(cntB, (unsigned)(kNB * t)); // y2[t-1] ready
            const unsigned* y2src = (const unsigned*)(
                t ? y2pp + (size_t)((t - 1) & 1) * kBH : h0bf + kBH);
            stage64k(y2src, ldsbuf);
            __syncthreads();
            mfma_phase(ldsbuf, a0base, a1base, aswz, Rf, acc0, acc1);
            __syncthreads();
#pragma unroll
            for (int r = 0; r < 4; r++) {
                pall[(((s * 4 + g) * 32) + crow + r) * 17 + ccol] = acc0[r];
                pall[(((s * 4 + g) * 32) + crow + r + 16) * 17 + ccol] = acc1[r];
            }
            __syncthreads();
            if (tid < 256) {
                float v[4][2];
#pragma unroll
                for (int gg = 0; gg < 4; gg++) {
                    float s0 = 0.f, s1 = 0.f;
#pragma unroll
                    for (int ss = 0; ss < 4; ss++) {
                        const int base = ((ss * 4 + gg) * 32 + eb) * 17 + ecp;
                        s0 += pall[base];
                        s1 += pall[base + 1];
                    }
                    v[gg][0] = s0 + ebias[gg][0];
                    v[gg][1] = s1 + ebias[gg][1];
                }
                creg0 = sigmoidf(v[1][0]) * creg0 + sigmoidf(v[0][0]) * tanhf(v[2][0]);
                creg1 = sigmoidf(v[1][1]) * creg1 + sigmoidf(v[0][1]) * tanhf(v[2][1]);
                const float y0 = sigmoidf(v[3][0]) * tanhf(creg0);
                const float y1v = sigmoidf(v[3][1]) * tanhf(creg1);
                union { bf16 b[2]; unsigned u; } pk;
                pk.b[0] = __float2bfloat16(y0);
                pk.b[1] = __float2bfloat16(y1v);
                __hip_atomic_store(
                    (unsigned*)(y2pp + (size_t)(t & 1) * kBH + (size_t)eb * kH + u0 + ecp),
                    pk.u, __ATOMIC_RELAXED, __HIP_MEMORY_SCOPE_AGENT);
                float* od = outf + (size_t)t * kBH + (size_t)eb * kH + u0 + ecp;
                od[0] = y0;
                od[1] = y1v;
            }
            if (t != kT - 1) grid_arrive(cntB);
        }
        if (tid < 256) {
            cst[kBH + (size_t)eb * kH + u0 + ecp] = creg0;
            cst[kBH + (size_t)eb * kH + u0 + ecp + 1] = creg1;
        }
    }
}

// ---------- legacy per-step kernel (Path B fallback) ----------
template <bool FUSED>
__global__ __launch_bounds__(256)
void lstm_step_mfma(const float* __restrict__ gx,
                    const bf16* __restrict__ xbf,
                    const bf16* __restrict__ Wbf,
                    const float* __restrict__ b1,
                    const float* __restrict__ b2,
                    const bf16* __restrict__ Rbf,
                    const bf16* __restrict__ ysrc,
                    bf16* __restrict__ ydst_bf,
                    float* __restrict__ ydst_f,
                    float* __restrict__ cst) {
    const int lane = threadIdx.x & 63, w = threadIdx.x >> 6;
    const int u0 = blockIdx.x << 4;
    const int fr = lane & 15, kq = (lane >> 4) << 3;
    const int n = w * kH + u0;
    f32x4 acc0 = {0.f, 0.f, 0.f, 0.f}, acc1 = {0.f, 0.f, 0.f, 0.f};
    {
        const bf16* Bp = Rbf + (size_t)(n + fr) * kH + kq;
        const bf16* A0 = ysrc + (size_t)fr * kH + kq;
        const bf16* A1 = ysrc + (size_t)(16 + fr) * kH + kq;
#pragma unroll 4
        for (int k = 0; k < kH; k += 32) {
            short8 bfrag = ld8(Bp + k);
            short8 a0 = ld8(A0 + k);
            short8 a1 = ld8(A1 + k);
            acc0 = mfma16(a0, bfrag, acc0);
            acc1 = mfma16(a1, bfrag, acc1);
        }
    }
    if (FUSED) {
        const bf16* Bp = Wbf + (size_t)(n + fr) * kIN + kq;
        const bf16* A0 = xbf + (size_t)fr * kIN + kq;
        const bf16* A1 = xbf + (size_t)(16 + fr) * kIN + kq;
#pragma unroll 4
        for (int k = 0; k < kIN; k += 32) {
            short8 bfrag = ld8(Bp + k);
            short8 a0 = ld8(A0 + k);
            short8 a1 = ld8(A1 + k);
            acc0 = mfma16(a0, bfrag, acc0);
            acc1 = mfma16(a1, bfrag, acc1);
        }
    }
    __shared__ float pre[4][kB][16];
    const int crow = (lane >> 4) << 2, ccol = lane & 15;
#pragma unroll
    for (int r = 0; r < 4; r++) {
        const int b = crow + r;
        float e0, e1;
        if (FUSED) {
            const float bias = b1[n + ccol] + b2[n + ccol];
            e0 = bias; e1 = bias;
        } else {
            e0 = gx[(size_t)b * kG + n + ccol];
            e1 = gx[(size_t)(b + 16) * kG + n + ccol];
        }
        pre[w][b][ccol] = acc0[r] + e0;
        pre[w][b + 16][ccol] = acc1[r] + e1;
    }
    __syncthreads();
    for (int idx = threadIdx.x; idx < kB * 16; idx += 256) {
        const int b = idx >> 4, col = idx & 15;
        const int u = u0 + col;
        const float iv = sigmoidf(pre[0][b][col]);
        const float fv = sigmoidf(pre[1][b][col]);
        const float gv = tanhf(pre[2][b][col]);
        const float ov = sigmoidf(pre[3][b][col]);
        const size_t off = (size_t)b * kH + u;
        const float c = fv * cst[off] + iv * gv;
        const float y = ov * tanhf(c);
        cst[off] = c;
        ydst_bf[off] = __float2bfloat16(y);
        if (ydst_f) ydst_f[off] = y;
    }
}

__global__ void finalize_bf(const bf16* __restrict__ y1last,
                            const float* __restrict__ cst,
                            float* __restrict__ out) {
    const int idx = blockIdx.x * blockDim.x + threadIdx.x;
    if (idx >= 2 * kBH) return;
    const float hv = (idx < kBH)
        ? __bfloat162float(y1last[idx])
        : out[(size_t)(kT - 1) * kBH + (idx - kBH)];
    out[(size_t)kT * kBH + idx] = hv;
    out[(size_t)kT * kBH + 2 * kBH + idx] = cst[idx];
}

// ---------- round-9 naive fallback (proven correct, 512 KB ws) ----------
__global__ __launch_bounds__(128)
void lstm_step_naive(const float* __restrict__ xA, const float* __restrict__ Wm,
                     const float* __restrict__ bWv, const float* __restrict__ bRv,
                     const float* __restrict__ Rm, const float* __restrict__ ysrc,
                     float* __restrict__ ydst, float* __restrict__ cst) {
    const int tid = threadIdx.x;
    const int b0 = (blockIdx.x & 1) << 4;
    const int bl = tid & 15;
    const int b  = b0 + bl;
    const int u  = ((blockIdx.x >> 1) << 3) + (tid >> 4);
    __shared__ float As[16][129];
    float acc[4] = {0.f, 0.f, 0.f, 0.f};
    const float* wrow[4];
#pragma unroll
    for (int g = 0; g < 4; g++) wrow[g] = Wm + (size_t)(g * kH + u) * 1024;
    for (int k0 = 0; k0 < 1024; k0 += 128) {
        __syncthreads();
        for (int i = tid; i < 16 * 128; i += 128)
            As[i >> 7][i & 127] = xA[(size_t)(b0 + (i >> 7)) * 1024 + k0 + (i & 127)];
        __syncthreads();
#pragma unroll 4
        for (int k = 0; k < 128; k += 4) {
            const float a0 = As[bl][k], a1 = As[bl][k + 1];
            const float a2 = As[bl][k + 2], a3 = As[bl][k + 3];
#pragma unroll
            for (int g = 0; g < 4; g++) {
                const float4 w4 = *reinterpret_cast<const float4*>(wrow[g] + k0 + k);
                acc[g] += a0 * w4.x + a1 * w4.y + a2 * w4.z + a3 * w4.w;
            }
        }
    }
#pragma unroll
    for (int g = 0; g < 4; g++) wrow[g] = Rm + (size_t)(g * kH + u) * 1024;
    for (int k0 = 0; k0 < 1024; k0 += 128) {
        __syncthreads();
        for (int i = tid; i < 16 * 128; i += 128)
            As[i >> 7][i & 127] = ysrc[(size_t)(b0 + (i >> 7)) * 1024 + k0 + (i & 127)];
        __syncthreads();
#pragma unroll 4
        for (int k = 0; k < 128; k += 4) {
            const float a0 = As[bl][k], a1 = As[bl][k + 1];
            const float a2 = As[bl][k + 2], a3 = As[bl][k + 3];
#pragma unroll
            for (int g = 0; g < 4; g++) {
                const float4 w4 = *reinterpret_cast<const float4*>(wrow[g] + k0 + k);
                acc[g] += a0 * w4.x + a1 * w4.y + a2 * w4.z + a3 * w4.w;
            }
        }
    }
#pragma unroll
    for (int g = 0; g < 4; g++) acc[g] += bWv[g * kH + u] + bRv[g * kH + u];
    const float iv = sigmoidf(acc[0]);
    const float fv = sigmoidf(acc[1]);
    const float gv = tanhf(acc[2]);
    const float ov = sigmoidf(acc[3]);
    const size_t off = (size_t)b * kH + u;
    const float c = fv * cst[off] + iv * gv;
    const float y = ov * tanhf(c);
    cst[off] = c;
    ydst[off] = y;
}

__global__ void finalize_f32(const float* __restrict__ y1last,
                             const float* __restrict__ cst,
                             float* __restrict__ out) {
    const int idx = blockIdx.x * blockDim.x + threadIdx.x;
    if (idx >= 2 * kBH) return;
    const float hv = (idx < kBH) ? y1last[idx]
                                 : out[(size_t)(kT - 1) * kBH + (idx - kBH)];
    out[(size_t)kT * kBH + idx] = hv;
    out[(size_t)kT * kBH + 2 * kBH + idx] = cst[idx];
}

extern "C" void kernel_launch(void* const* d_in, const int* in_sizes, int n_in,
                              void* d_out, int out_size, void* d_ws, size_t ws_size,
                              hipStream_t stream) {
    (void)in_sizes; (void)n_in; (void)out_size;
    const float* x   = (const float*)d_in[0];
    const float* h0  = (const float*)d_in[1];
    const float* c0  = (const float*)d_in[2];
    const float* W0  = (const float*)d_in[3];
    const float* R0  = (const float*)d_in[4];
    const float* bW0 = (const float*)d_in[5];
    const float* bR0 = (const float*)d_in[6];
    const float* W1  = (const float*)d_in[7];
    const float* R1  = (const float*)d_in[8];
    const float* bW1 = (const float*)d_in[9];
    const float* bR1 = (const float*)d_in[10];
    float* out = (float*)d_out;
    char* wsp = (char*)d_ws;

    const size_t gxB  = (size_t)kT * kB * kG * 4;   // 134,217,728
    const size_t xbfB = (size_t)kT * kBH * 2;       //  16,777,216
    const size_t wB   = (size_t)kG * kH * 2;        //   8,388,608 each
    const size_t hbfB = 2 * (size_t)kBH * 2;        //     131,072
    const size_t ppB  = 2 * (size_t)kBH * 2;        //     131,072
    const size_t cstB = 2 * (size_t)kBH * 4;        //     262,144
    const size_t barB = 256;                        // cntA=bar[0], cntB=bar[16]
    const size_t needA = gxB + 2 * xbfB + 4 * wB + hbfB + ppB + cstB + barB;
    const size_t needB = xbfB + 4 * wB + hbfB + 2 * ppB + cstB;

    const dim3 cvB(256), fiG((2 * kBH + 255) / 256);

    if (ws_size >= needA) {
        // ---- Path A: gx precompute (layer 1) + fused pipelined 2-layer scan ----
        float* gx    = (float*)wsp;
        bf16*  xbf   = (bf16*)(wsp + gxB);
        bf16*  y1seq = (bf16*)(wsp + gxB + xbfB);
        bf16*  Wb0   = (bf16*)(wsp + gxB + 2 * xbfB);
        bf16*  Rb0   = (bf16*)((char*)Wb0 + wB);
        bf16*  Wb1   = (bf16*)((char*)Wb0 + 2 * wB);
        bf16*  Rb1   = (bf16*)((char*)Wb0 + 3 * wB);
        bf16*  hbf   = (bf16*)((char*)Wb0 + 4 * wB);
        bf16*  y2pp  = (bf16*)((char*)hbf + hbfB);
        float* cst   = (float*)((char*)y2pp + ppB);
        unsigned* bar = (unsigned*)((char*)cst + cstB);

        hipMemsetAsync(bar, 0, barB, stream);
        cvt_f32_bf16<<<dim3(1024), cvB, 0, stream>>>(x, xbf, kT * kBH);
        cvt_f32_bf16<<<dim3(1024), cvB, 0, stream>>>(W0, Wb0, kG * kH);
        cvt_f32_bf16<<<dim3(1024), cvB, 0, stream>>>(R0, Rb0, kG * kH);
        cvt_f32_bf16<<<dim3(1024), cvB, 0, stream>>>(W1, Wb1, kG * kH);
        cvt_f32_bf16<<<dim3(1024), cvB, 0, stream>>>(R1, Rb1, kG * kH);
        cvt_f32_bf16<<<dim3(64), cvB, 0, stream>>>(h0, hbf, 2 * kBH);

        gemm_bias<<<dim3((kT * kB / 64) * (kG / 64)), dim3(64), 0, stream>>>(
            xbf, Wb0, bW0, bR0, gx, kT * kB, kG, kIN);
        lstm_fused<<<dim3(2 * kNB), dim3(1024), 0, stream>>>(
            gx, Rb0, Wb1, Rb1, bW1, bR1, hbf, c0,
            y1seq, y2pp, out, cst, bar, bar + 16);
        finalize_bf<<<fiG, dim3(256), 0, stream>>>(
            y1seq + (size_t)(kT - 1) * kBH, cst, out);
    } else if (ws_size >= needB) {
        // ---- Path B: fused W-matmul per step ----
        bf16*  xbf  = (bf16*)wsp;
        bf16*  Wb0  = (bf16*)(wsp + xbfB);
        bf16*  Rb0  = (bf16*)((char*)Wb0 + wB);
        bf16*  Wb1  = (bf16*)((char*)Wb0 + 2 * wB);
        bf16*  Rb1  = (bf16*)((char*)Wb0 + 3 * wB);
        bf16*  hbf  = (bf16*)((char*)Wb0 + 4 * wB);
        bf16*  y1pp = (bf16*)((char*)hbf + hbfB);
        bf16*  y2pp = (bf16*)((char*)y1pp + ppB);
        float* cst  = (float*)((char*)y2pp + ppB);

        cvt_f32_bf16<<<dim3(1024), cvB, 0, stream>>>(x, xbf, kT * kBH);
        cvt_f32_bf16<<<dim3(1024), cvB, 0, stream>>>(W0, Wb0, kG * kH);
        cvt_f32_bf16<<<dim3(1024), cvB, 0, stream>>>(R0, Rb0, kG * kH);
        cvt_f32_bf16<<<dim3(1024), cvB, 0, stream>>>(W1, Wb1, kG * kH);
        cvt_f32_bf16<<<dim3(1024), cvB, 0, stream>>>(R1, Rb1, kG * kH);
        cvt_f32_bf16<<<dim3(64), cvB, 0, stream>>>(h0, hbf, 2 * kBH);
        hipMemcpyAsync(cst, c0, cstB, hipMemcpyDeviceToDevice, stream);

        for (int t = 0; t < kT; t++) {
            const bf16* ys0 = t ? y1pp + (size_t)((t - 1) & 1) * kBH : hbf;
            bf16* y1t = y1pp + (size_t)(t & 1) * kBH;
            lstm_step_mfma<true><<<dim3(kNB), dim3(256), 0, stream>>>(
                nullptr, xbf + (size_t)t * kBH, Wb0, bW0, bR0,
                Rb0, ys0, y1t, nullptr, cst);
            const bf16* ys1 = t ? y2pp + (size_t)((t - 1) & 1) * kBH : hbf + kBH;
            lstm_step_mfma<true><<<dim3(kNB), dim3(256), 0, stream>>>(
                nullptr, y1t, Wb1, bW1, bR1,
                Rb1, ys1, y2pp + (size_t)(t & 1) * kBH,
                out + (size_t)t * kBH, cst + kBH);
        }
        finalize_bf<<<fiG, dim3(256), 0, stream>>>(
            y1pp + (size_t)((kT - 1) & 1) * kBH, cst, out);
    } else {
        // ---- Path C: round-9 naive fp32 (proven) ----
        float* y1pp = (float*)wsp;
        float* cst  = y1pp + 2 * (size_t)kBH;
        hipMemcpyAsync(cst, c0, cstB, hipMemcpyDeviceToDevice, stream);
        for (int t = 0; t < kT; t++) {
            const float* ys0 = t ? y1pp + (size_t)((t - 1) & 1) * kBH : h0;
            float* y1t = y1pp + (size_t)(t & 1) * kBH;
            lstm_step_naive<<<dim3(256), dim3(128), 0, stream>>>(
                x + (size_t)t * kB * kIN, W0, bW0, bR0, R0, ys0, y1t, cst);
            const float* ys1 = t ? out + (size_t)(t - 1) * kBH : h0 + kBH;
            lstm_step_naive<<<dim3(256), dim3(128), 0, stream>>>(
                y1t, W1, bW1, bR1, R1, ys1, out + (size_t)t * kBH, cst + kBH);
        }
        finalize_f32<<<fiG, dim3(256), 0, stream>>>(
            y1pp + (size_t)((kT - 1) & 1) * kBH, cst, out);
    }
}